// Round 12
// baseline (155.518 us; speedup 1.0000x reference)
//
#include <hip/hip_runtime.h>
#include <string.h>

// Integer-quantized MHA. R23 = R18 artifact (best: mha 57.6us) with ONE change:
// __launch_bounds__ (256,3) -> (256,4).
// Evidence: every (256,4) build measured ~39-40% occupancy (3 blocks/CU: R7,
// R13, R14); both (256,3) builds measured ~25% (2 blocks: R18, R21). R18's
// fenced-prefetch win paid a hidden occupancy tax; bf16 path needs only
// VGPR=68, far under (256,4)'s 128 cap, so the tax buys nothing. Stall profile
// (VALU 33%, MFMA 11%, HBM 7.5% -> 55% stall = per-wave L2 latency) is exactly
// what +50% TLP (2->3 blocks) fills. R21's depth-2/setprio/early-hoist all
// measured neutral-to-negative (VGPR 72: depth-2 buffers never materialized)
// -> reverted; this round isolates the single occupancy variable.
// Phase 1: transposed bf16 MFMA (exact: K/Q values <=8 sig bits; products
// exact in f32; scores sigma~1.3e6 << 2^24) + fenced depth-1 prefetch.
// Softmax float-domain; R13 requant/XOR-swizzle/32KB LDS; phase-2 fenced
// ping-pong with group-0 vd loads hoisted above requant (T14).
// Closed axes: TT=32 (R9/R12), LDS conflicts (R4/R5), LDS-size occupancy (R7),
// bf16-no-prefetch (R14), unfenced prefetch (R16), depth-2/setprio (R21).
// B=2,H=16 (BH=32), T=S=1024, HC=128, G=8. Output int32.

typedef int   v4i __attribute__((ext_vector_type(4)));
typedef float v4f __attribute__((ext_vector_type(4)));
typedef short v8s __attribute__((ext_vector_type(8)));
typedef unsigned v2u __attribute__((ext_vector_type(2)));

#define BHN 32
#define TN  1024
#define SN  1024
#define HCN 128
#define TT  16
#define KD_BH 262144           // 8 ch * 8 n * 4 kc * 64 lanes * 16 B (bf16 frags)
#define VD_BH 262144           // 32 kb * 8 n * 64 lanes * 16 B (bf16 frags)
#define WS_NEED ((size_t)BHN*(KD_BH+VD_BH))   // 16 MB

__device__ __forceinline__ unsigned short bf16_of_int(int v){
    return (unsigned short)(__float_as_uint((float)v) >> 16);   // exact: <=8 sig bits
}

// pack 8 consecutive dequantized ints (one scale group) into 4 bf16x2 words
__device__ __forceinline__ v4i pack8(const int* __restrict__ p, int s){
    unsigned wd[4];
    #pragma unroll
    for (int j=0;j<4;j++){
        int a = p[j*2]   << s;
        int b = p[j*2+1] << s;
        wd[j] = (unsigned)bf16_of_int(a) | ((unsigned)bf16_of_int(b) << 16);
    }
    return v4i{(int)wd[0],(int)wd[1],(int)wd[2],(int)wd[3]};
}

// ---------------- pre-pass (gather form: coalesced stores) ----------------
// kd: per bh, [ch(8)][n(8)][kc(4)][lane64][16B] bf16 A-frags (K=32 chunks).
// vd: per bh, [kb(32)][n(8)][lane64][16B] bf16 B-frags.
// One wave per fragment tile: lane stores base+lane*16 -> 1KB wave-stores.
// Tasks: 0..8191 = kd; 8192..16383 = vd.
__global__ __launch_bounds__(256) void digitize(
    const int* __restrict__ k_q, const int* __restrict__ k_s,
    const int* __restrict__ vt_q, const int* __restrict__ vt_s,
    unsigned char* __restrict__ kd, unsigned char* __restrict__ vd)
{
    const int w    = threadIdx.x >> 6;
    const int lane = threadIdx.x & 63;
    const int l15  = lane & 15;
    const int q4   = lane >> 4;
    const int task = blockIdx.x*4 + w;
    if (task < 8192){
        const int kc = task & 3, n = (task>>2)&7, ch = (task>>5)&7, bh = task>>8;
        const int row = bh*SN + ch*128 + n*16 + l15;
        const int col = kc*32 + q4*8;
        v4i f = pack8(k_q + (size_t)row*HCN + col, k_s[row*16 + (col>>3)]);
        size_t base = (size_t)bh*KD_BH + (size_t)((((ch*8+n)*4 + kc)*64 + lane)*16);
        *(v4i*)(kd + base) = f;             // 1KB coalesced wave store
    } else {
        const int t  = task - 8192;
        const int n  = t & 7, kb = (t>>3)&31, bh = t>>8;
        const int row = bh*HCN + n*16 + l15;       // vt channel row
        v4i f = pack8(vt_q + (size_t)row*SN + kb*32 + q4*8,
                      vt_s[row*128 + kb*4 + q4]);
        size_t base = (size_t)bh*VD_BH + (size_t)(((kb*8 + n)*64 + lane)*16);
        *(v4i*)(vd + base) = f;
    }
}

// ---------------- main fused kernel ----------------
template<bool PK>
__global__ __launch_bounds__(256,4) void mha_mfma(
    const int* __restrict__ q_q, const int* __restrict__ q_s,
    const int* __restrict__ k_q, const int* __restrict__ k_s,
    const int* __restrict__ vt_q, const int* __restrict__ vt_s,
    const unsigned char* __restrict__ kd, const unsigned char* __restrict__ vd,
    int* __restrict__ out)
{
    // EXACTLY 32 KB (R13 artifact).
    __shared__ __align__(16) unsigned short rbuf[16*1024];
    // reduction scratch carved into rbuf row 15 cols 768..1023 (dead until
    // requant, which overwrites it only after bar3).
    float* redm = (float*)(rbuf + 16128);   // 64 floats: row-max partials
    float* redf = (float*)(rbuf + 16256);   // 64 floats: row-sum partials

    const int tid  = threadIdx.x;
    const int ln   = tid & 15;
    const int qd4  = (tid >> 4) & 3;
    const int w    = tid >> 6;
    const int lane = tid & 63;
    // XCD-aware swizzle: each XCD's share covers only 4 bh -> digit images fit its L2.
    const int blk = blockIdx.x;
    const int bh  = ((blk>>9)<<3) | (blk&7);
    const int t0  = ((blk>>3)&63) * TT;

    // ---- Q fragments in registers (B operand in phase 1, t=ln), bf16 exact ----
    v8s qf[4];
    {
        const int* qrow = q_q + (size_t)(bh*TN + t0 + ln)*HCN;
        const int* qs   = q_s + (size_t)(bh*TN + t0 + ln)*16;
        #pragma unroll
        for (int kc=0; kc<4; ++kc){
            int col = kc*32 + qd4*8;
            v4i t = pack8(qrow + col, qs[col>>3]);
            memcpy(&qf[kc], &t, 16);
        }
    }

    v4f scv[16];   // C[s][t]: s = (ch*8 + w*2 + i)*16 + qd4*4 + r, t = ln
                   // EXACT integer scores in f32

    // ========== phase 1: QK^T, transposed bf16 MFMA, fenced depth-1 prefetch ==========
    const v4i* kb_ = (const v4i*)(kd + (size_t)bh*KD_BH);
    if (PK){
        v4i fb[2][4];    // [parity][kc] -- one tile = 4 fragments
        {   // prologue: tile 0 (ch=0, i=0, n=w*2)
            const v4i* ta = kb_ + ((w*2)*4)*64 + lane;
            fb[0][0]=ta[0]; fb[0][1]=ta[64]; fb[0][2]=ta[128]; fb[0][3]=ta[192];
        }
        #pragma unroll
        for (int t=0; t<16; ++t){
            const int par = t & 1;
            if (t < 15){
                const int t1 = t+1, ch1 = t1>>1, i1 = t1&1;
                const v4i* ta = kb_ + ((ch1*8 + w*2 + i1)*4)*64 + lane;
                fb[par^1][0]=ta[0];   fb[par^1][1]=ta[64];
                fb[par^1][2]=ta[128]; fb[par^1][3]=ta[192];
            }
            // Pin: loads above issue BEFORE the MFMAs below -> counted vmcnt,
            // next tile's 4 loads stay in flight across this tile's compute.
            __builtin_amdgcn_sched_barrier(0);
            v4f acc{0.f,0.f,0.f,0.f};
            #pragma unroll
            for (int kc=0;kc<4;kc++){
                v8s af;
                memcpy(&af, &fb[par][kc], 16);
                acc = __builtin_amdgcn_mfma_f32_16x16x32_bf16(af, qf[kc], acc, 0,0,0);
            }
            scv[t] = acc;
        }
    } else {
        for (int ch=0; ch<8; ++ch){
            #pragma unroll
            for (int i=0;i<2;i++){
                const int n = w*2 + i;
                v4f acc{0.f,0.f,0.f,0.f};
                #pragma unroll
                for (int kc=0;kc<4;kc++){
                    int srow = bh*SN + ch*128 + n*16 + ln;
                    int cc   = kc*32 + qd4*8;
                    v4i a_ = pack8(k_q + (size_t)srow*HCN + cc,
                                   k_s[srow*16 + (cc>>3)]);
                    v8s af;
                    memcpy(&af, &a_, 16);
                    acc = __builtin_amdgcn_mfma_f32_16x16x32_bf16(af, qf[kc], acc, 0,0,0);
                }
                scv[ch*2 + i] = acc;
            }
        }
    }

    // ================= softmax over s (float max, log2-domain exp) =================
    // Scores are exact ints in f32; (s - m) subtraction exact at these magnitudes.
    const float CS2 = (float)(6.103515625e-05 / 11.313708498984760390566
                              * 1.4426950408889634074);
    {
        float m0=-3.0e38f, m1=-3.0e38f, m2=-3.0e38f, m3=-3.0e38f;
        #pragma unroll
        for (int st=0;st<16;st++){
            m0 = fmaxf(m0, scv[st][0]);
            m1 = fmaxf(m1, scv[st][1]);
            m2 = fmaxf(m2, scv[st][2]);
            m3 = fmaxf(m3, scv[st][3]);
        }
        float m_ = fmaxf(fmaxf(m0,m1), fmaxf(m2,m3));
        m_ = fmaxf(m_, __shfl_xor(m_, 16));
        m_ = fmaxf(m_, __shfl_xor(m_, 32));
        if ((tid & 48) == 0) redm[w*16 + ln] = m_;
    }
    __syncthreads();                                  // bar1: redm visible
    float inv14;
    {
        const float mrow = fmaxf(fmaxf(redm[ln], redm[16+ln]),
                                 fmaxf(redm[32+ln], redm[48+ln]));
        float s0=0.f, s1=0.f, s2=0.f, s3=0.f;
        #pragma unroll
        for (int st=0;st<16;st++){
            #pragma unroll
            for (int r=0;r<4;r++){
                float t_ = (scv[st][r] - mrow) * CS2;          // <= 0, sub exact
                float e;
                asm("v_exp_f32 %0, %1" : "=v"(e) : "v"(t_));   // 2^t
                scv[st][r] = e;
                if (r==0) s0 += e; else if (r==1) s1 += e; else if (r==2) s2 += e; else s3 += e;
            }
        }
        float s_ = (s0+s1) + (s2+s3);
        s_ += __shfl_xor(s_, 16);
        s_ += __shfl_xor(s_, 32);
        if ((tid & 48) == 0) redf[w*16 + ln] = s_;
    }
    __syncthreads();                                  // bar2: redf visible
    {
        float sum = redf[ln] + redf[16+ln] + redf[32+ln] + redf[48+ln];
        inv14 = 16384.0f / sum;        // one IEEE div per thread
    }
    __syncthreads();                                  // bar3: sum-reads done before
                                                      // requant overwrites row 15

    // ---- T14 async-stage: issue phase-2 group-0 vd loads NOW, fenced so they
    // can't sink; ~200cyc L2 latency hides under the requant VALU below.
    const v4i* vb = (const v4i*)(vd + (size_t)bh*VD_BH);
    v4i gb[2][8];
    v8s ga[2][4];
    if (PK){
        #pragma unroll
        for (int j=0;j<4;j++){
            gb[0][j*2]   = vb[(j*8 + w*2    )*64 + lane];
            gb[0][j*2+1] = vb[(j*8 + w*2 + 1)*64 + lane];
        }
        __builtin_amdgcn_sched_barrier(0);
    }

    // ======== group-of-8 po2 requant, in registers -> b64 rbuf stores ========
    // granule = thread's 4 s-values + partner at lane^16; gmax <= 255<<sh so no clamp.
    // XOR swizzle c' = c ^ ((ln&7)<<4) on unpadded 2048B rows (R13-validated).
    {
        const int lnr4 = (ln & 7) << 4;
        const int cbase = w*32 + qd4*4;
        unsigned short* rp = rbuf + ln*1024;
        #pragma unroll
        for (int st=0;st<16;st++){
            float v0 = rintf(scv[st][0] * inv14);
            float v1 = rintf(scv[st][1] * inv14);
            float v2 = rintf(scv[st][2] * inv14);
            float v3 = rintf(scv[st][3] * inv14);
            float g = fmaxf(fmaxf(v0,v1), fmaxf(v2,v3));
            g = fmaxf(g, __shfl_xor(g, 16));            // partner half of the granule
            int gi = max((int)g, 1);
            int x  = gi - 1;
            int e2 = 31 - __clz(x | 255);
            int sh = (e2 - 7) + ((x >> (e2 - 7)) == 255); // clip(ceil(log2(gi/255)),0,)
            float isc = __int_as_float((127 - sh) << 23); // exact 2^-sh
            float fsc = __int_as_float((127 + sh) << 23); // exact 2^sh
            unsigned b0 = __float_as_uint(rintf(v0*isc) * fsc);  // r = rq<<sh, 8 sig bits
            unsigned b1 = __float_as_uint(rintf(v1*isc) * fsc);
            unsigned b2 = __float_as_uint(rintf(v2*isc) * fsc);
            unsigned b3 = __float_as_uint(rintf(v3*isc) * fsc);
            unsigned w0 = __builtin_amdgcn_perm(b1, b0, 0x07060302u); // {bf16(v0),bf16(v1)}
            unsigned w1 = __builtin_amdgcn_perm(b3, b2, 0x07060302u);
            int c0 = (st>>1)*128 + cbase + (st&1)*16;   // col of v0 (u16 units, 4-aligned)
            *(v2u*)(rp + (c0 ^ lnr4)) = v2u{w0, w1};    // one swizzled b64 store per tile
        }
    }
    __syncthreads();                                  // bar4: rbuf ready

    // ================= phase 2: out = r @ vt^T (bf16 MFMA, fenced ping-pong) =========
    const unsigned short* rp2 = rbuf + ln*1024;
    const int lnr4b = (ln & 7) << 4;
    v4f acc0{0,0,0,0}, acc1{0,0,0,0};
    if (PK){
        #pragma unroll
        for (int j=0;j<4;j++)
            ga[0][j] = *(const v8s*)(rp2 + ((j*32 + qd4*8) ^ lnr4b));
        #pragma unroll
        for (int g=0; g<8; ++g){
            const int par = g & 1;
            if (g < 7){
                #pragma unroll
                for (int j=0;j<4;j++){
                    int kb = (g+1)*4 + j;
                    gb[par^1][j*2]   = vb[(kb*8 + w*2    )*64 + lane];
                    gb[par^1][j*2+1] = vb[(kb*8 + w*2 + 1)*64 + lane];
                    ga[par^1][j] = *(const v8s*)(rp2 + ((kb*32 + qd4*8) ^ lnr4b));
                }
            }
            __builtin_amdgcn_sched_barrier(0);        // pin loads before MFMAs
            #pragma unroll
            for (int j=0;j<4;j++){
                v8s bs0, bs1;
                memcpy(&bs0, &gb[par][j*2],   16);
                memcpy(&bs1, &gb[par][j*2+1], 16);
                acc0 = __builtin_amdgcn_mfma_f32_16x16x32_bf16(ga[par][j], bs0, acc0, 0,0,0);
                acc1 = __builtin_amdgcn_mfma_f32_16x16x32_bf16(ga[par][j], bs1, acc1, 0,0,0);
            }
        }
    } else {
        #pragma unroll 4
        for (int kb=0; kb<32; ++kb){
            v8s af = *(const v8s*)(rp2 + ((kb*32 + qd4*8) ^ lnr4b));
            v4i b0, b1;
            #pragma unroll
            for (int i=0;i<2;i++){
                int chan = (w*2+i)*16 + ln;
                v4i t = pack8(vt_q + (size_t)(bh*HCN + chan)*SN + kb*32 + qd4*8,
                              vt_s[(bh*HCN + chan)*128 + kb*4 + qd4]);
                if (i==0) b0 = t; else b1 = t;
            }
            v8s bs0, bs1;
            memcpy(&bs0, &b0, 16);
            memcpy(&bs1, &b1, 16);
            acc0 = __builtin_amdgcn_mfma_f32_16x16x32_bf16(af, bs0, acc0, 0,0,0);
            acc1 = __builtin_amdgcn_mfma_f32_16x16x32_bf16(af, bs1, acc1, 0,0,0);
        }
    }
    #pragma unroll
    for (int r=0;r<4;r++){
        size_t o = (size_t)(bh*TN + t0 + qd4*4 + r)*HCN + w*32 + ln;
        out[o]      = (int)rintf(acc0[r]);
        out[o + 16] = (int)rintf(acc1[r]);
    }
}

extern "C" void kernel_launch(void* const* d_in, const int* in_sizes, int n_in,
                              void* d_out, int out_size, void* d_ws, size_t ws_size,
                              hipStream_t stream) {
    const int* q_q  = (const int*)d_in[0];
    const int* q_s  = (const int*)d_in[1];
    const int* k_q  = (const int*)d_in[2];
    const int* k_s  = (const int*)d_in[3];
    const int* vt_q = (const int*)d_in[4];
    const int* vt_s = (const int*)d_in[5];
    int* out = (int*)d_out;

    unsigned char* kd = (unsigned char*)d_ws;
    unsigned char* vd = kd + (size_t)BHN*KD_BH;

    if (ws_size >= WS_NEED){
        // 16384 wave-tasks (8192 kd + 8192 vd), 4 waves/block
        digitize<<<dim3(4096), 256, 0, stream>>>(k_q,k_s,vt_q,vt_s, kd,vd);
        mha_mfma<true><<<dim3(2048), 256, 0, stream>>>(
            q_q,q_s,k_q,k_s,vt_q,vt_s, kd,vd, out);
    } else {
        mha_mfma<false><<<dim3(2048), 256, 0, stream>>>(
            q_q,q_s,k_q,k_s,vt_q,vt_s, kd,vd, out);
    }
}

// Round 13
// 147.008 us; speedup vs baseline: 1.0579x; 1.0579x over previous
//
#include <hip/hip_runtime.h>
#include <string.h>

// Integer-quantized MHA. R25 = R18 artifact (best: mha 57.6us) with phase-2
// register footprint halved so __launch_bounds__(256,4) fits WITHOUT spill.
// Evidence chain:
//  - R23 ((256,4) on R18 verbatim): occupancy 25.7->34% as predicted, but
//    WRITE_SIZE 16384->32768KB + FETCH +6MB = scratch spill (phase-2 dbuf
//    gb[2][8]+ga[2][4]=48 regs over the tighter target) -> 64.8us regression.
//  - R25: phase-2 ping-pong groups-of-4 -> groups-of-2 (gb[2][4]+ga[2][2]=24
//    regs); T14 hoist preloads only kb0-1; separate redm/redf arrays (+512B
//    LDS=33280B, R5 proved 33792B still 3 blocks at (256,4)) -> bar3 deleted.
//  - Tripwires: WRITE_SIZE must be exactly 16384KB, occupancy ~39%. If spill
//    again or dur >= 57.6 at 39% occupancy, R18 is this structure's floor.
// Phase 1: transposed bf16 MFMA (exact: K/Q values <=8 sig bits; products
// exact in f32; scores sigma~1.3e6 << 2^24) + fenced depth-1 prefetch.
// Float softmax; R13 requant/XOR-swizzle; fenced phase-2 ping-pong.
// Closed axes: TT=32 (R9/R12), LDS conflicts (R4/R5), LDS-size (R7),
// bf16-no-prefetch (R14), unfenced prefetch (R16), depth-2/setprio (R21),
// (256,4)-with-fat-registers (R23).
// B=2,H=16 (BH=32), T=S=1024, HC=128, G=8. Output int32.

typedef int   v4i __attribute__((ext_vector_type(4)));
typedef float v4f __attribute__((ext_vector_type(4)));
typedef short v8s __attribute__((ext_vector_type(8)));
typedef unsigned v2u __attribute__((ext_vector_type(2)));

#define BHN 32
#define TN  1024
#define SN  1024
#define HCN 128
#define TT  16
#define KD_BH 262144           // 8 ch * 8 n * 4 kc * 64 lanes * 16 B (bf16 frags)
#define VD_BH 262144           // 32 kb * 8 n * 64 lanes * 16 B (bf16 frags)
#define WS_NEED ((size_t)BHN*(KD_BH+VD_BH))   // 16 MB

__device__ __forceinline__ unsigned short bf16_of_int(int v){
    return (unsigned short)(__float_as_uint((float)v) >> 16);   // exact: <=8 sig bits
}

// pack 8 consecutive dequantized ints (one scale group) into 4 bf16x2 words
__device__ __forceinline__ v4i pack8(const int* __restrict__ p, int s){
    unsigned wd[4];
    #pragma unroll
    for (int j=0;j<4;j++){
        int a = p[j*2]   << s;
        int b = p[j*2+1] << s;
        wd[j] = (unsigned)bf16_of_int(a) | ((unsigned)bf16_of_int(b) << 16);
    }
    return v4i{(int)wd[0],(int)wd[1],(int)wd[2],(int)wd[3]};
}

// ---------------- pre-pass (gather form: coalesced stores) ----------------
// kd: per bh, [ch(8)][n(8)][kc(4)][lane64][16B] bf16 A-frags (K=32 chunks).
// vd: per bh, [kb(32)][n(8)][lane64][16B] bf16 B-frags.
// One wave per fragment tile: lane stores base+lane*16 -> 1KB wave-stores.
// Tasks: 0..8191 = kd; 8192..16383 = vd.
__global__ __launch_bounds__(256) void digitize(
    const int* __restrict__ k_q, const int* __restrict__ k_s,
    const int* __restrict__ vt_q, const int* __restrict__ vt_s,
    unsigned char* __restrict__ kd, unsigned char* __restrict__ vd)
{
    const int w    = threadIdx.x >> 6;
    const int lane = threadIdx.x & 63;
    const int l15  = lane & 15;
    const int q4   = lane >> 4;
    const int task = blockIdx.x*4 + w;
    if (task < 8192){
        const int kc = task & 3, n = (task>>2)&7, ch = (task>>5)&7, bh = task>>8;
        const int row = bh*SN + ch*128 + n*16 + l15;
        const int col = kc*32 + q4*8;
        v4i f = pack8(k_q + (size_t)row*HCN + col, k_s[row*16 + (col>>3)]);
        size_t base = (size_t)bh*KD_BH + (size_t)((((ch*8+n)*4 + kc)*64 + lane)*16);
        *(v4i*)(kd + base) = f;             // 1KB coalesced wave store
    } else {
        const int t  = task - 8192;
        const int n  = t & 7, kb = (t>>3)&31, bh = t>>8;
        const int row = bh*HCN + n*16 + l15;       // vt channel row
        v4i f = pack8(vt_q + (size_t)row*SN + kb*32 + q4*8,
                      vt_s[row*128 + kb*4 + q4]);
        size_t base = (size_t)bh*VD_BH + (size_t)(((kb*8 + n)*64 + lane)*16);
        *(v4i*)(vd + base) = f;
    }
}

// ---------------- main fused kernel ----------------
template<bool PK>
__global__ __launch_bounds__(256,4) void mha_mfma(
    const int* __restrict__ q_q, const int* __restrict__ q_s,
    const int* __restrict__ k_q, const int* __restrict__ k_s,
    const int* __restrict__ vt_q, const int* __restrict__ vt_s,
    const unsigned char* __restrict__ kd, const unsigned char* __restrict__ vd,
    int* __restrict__ out)
{
    __shared__ __align__(16) unsigned short rbuf[16*1024];  // 32 KB r values (bf16)
    __shared__ float redm[64];   // row-max partials
    __shared__ float redf[64];   // row-sum partials

    const int tid  = threadIdx.x;
    const int ln   = tid & 15;
    const int qd4  = (tid >> 4) & 3;
    const int w    = tid >> 6;
    const int lane = tid & 63;
    // XCD-aware swizzle: each XCD's share covers only 4 bh -> digit images fit its L2.
    const int blk = blockIdx.x;
    const int bh  = ((blk>>9)<<3) | (blk&7);
    const int t0  = ((blk>>3)&63) * TT;

    // ---- Q fragments in registers (B operand in phase 1, t=ln), bf16 exact ----
    v8s qf[4];
    {
        const int* qrow = q_q + (size_t)(bh*TN + t0 + ln)*HCN;
        const int* qs   = q_s + (size_t)(bh*TN + t0 + ln)*16;
        #pragma unroll
        for (int kc=0; kc<4; ++kc){
            int col = kc*32 + qd4*8;
            v4i t = pack8(qrow + col, qs[col>>3]);
            memcpy(&qf[kc], &t, 16);
        }
    }

    v4f scv[16];   // C[s][t]: s = (ch*8 + w*2 + i)*16 + qd4*4 + r, t = ln
                   // EXACT integer scores in f32

    // ========== phase 1: QK^T, transposed bf16 MFMA, fenced depth-1 prefetch ==========
    const v4i* kb_ = (const v4i*)(kd + (size_t)bh*KD_BH);
    if (PK){
        v4i fb[2][4];    // [parity][kc] -- one tile = 4 fragments
        {   // prologue: tile 0 (ch=0, i=0, n=w*2)
            const v4i* ta = kb_ + ((w*2)*4)*64 + lane;
            fb[0][0]=ta[0]; fb[0][1]=ta[64]; fb[0][2]=ta[128]; fb[0][3]=ta[192];
        }
        #pragma unroll
        for (int t=0; t<16; ++t){
            const int par = t & 1;
            if (t < 15){
                const int t1 = t+1, ch1 = t1>>1, i1 = t1&1;
                const v4i* ta = kb_ + ((ch1*8 + w*2 + i1)*4)*64 + lane;
                fb[par^1][0]=ta[0];   fb[par^1][1]=ta[64];
                fb[par^1][2]=ta[128]; fb[par^1][3]=ta[192];
            }
            // Pin: loads above issue BEFORE the MFMAs below -> counted vmcnt,
            // next tile's 4 loads stay in flight across this tile's compute.
            __builtin_amdgcn_sched_barrier(0);
            v4f acc{0.f,0.f,0.f,0.f};
            #pragma unroll
            for (int kc=0;kc<4;kc++){
                v8s af;
                memcpy(&af, &fb[par][kc], 16);
                acc = __builtin_amdgcn_mfma_f32_16x16x32_bf16(af, qf[kc], acc, 0,0,0);
            }
            scv[t] = acc;
        }
    } else {
        for (int ch=0; ch<8; ++ch){
            #pragma unroll
            for (int i=0;i<2;i++){
                const int n = w*2 + i;
                v4f acc{0.f,0.f,0.f,0.f};
                #pragma unroll
                for (int kc=0;kc<4;kc++){
                    int srow = bh*SN + ch*128 + n*16 + ln;
                    int cc   = kc*32 + qd4*8;
                    v4i a_ = pack8(k_q + (size_t)srow*HCN + cc,
                                   k_s[srow*16 + (cc>>3)]);
                    v8s af;
                    memcpy(&af, &a_, 16);
                    acc = __builtin_amdgcn_mfma_f32_16x16x32_bf16(af, qf[kc], acc, 0,0,0);
                }
                scv[ch*2 + i] = acc;
            }
        }
    }

    // ================= softmax over s (float max, log2-domain exp) =================
    // Scores are exact ints in f32; (s - m) subtraction exact at these magnitudes.
    const float CS2 = (float)(6.103515625e-05 / 11.313708498984760390566
                              * 1.4426950408889634074);
    {
        float m0=-3.0e38f, m1=-3.0e38f, m2=-3.0e38f, m3=-3.0e38f;
        #pragma unroll
        for (int st=0;st<16;st++){
            m0 = fmaxf(m0, scv[st][0]);
            m1 = fmaxf(m1, scv[st][1]);
            m2 = fmaxf(m2, scv[st][2]);
            m3 = fmaxf(m3, scv[st][3]);
        }
        float m_ = fmaxf(fmaxf(m0,m1), fmaxf(m2,m3));
        m_ = fmaxf(m_, __shfl_xor(m_, 16));
        m_ = fmaxf(m_, __shfl_xor(m_, 32));
        if ((tid & 48) == 0) redm[w*16 + ln] = m_;
    }
    __syncthreads();                                  // bar1: redm visible
    float inv14;
    {
        const float mrow = fmaxf(fmaxf(redm[ln], redm[16+ln]),
                                 fmaxf(redm[32+ln], redm[48+ln]));
        float s0=0.f, s1=0.f, s2=0.f, s3=0.f;
        #pragma unroll
        for (int st=0;st<16;st++){
            #pragma unroll
            for (int r=0;r<4;r++){
                float t_ = (scv[st][r] - mrow) * CS2;          // <= 0, sub exact
                float e;
                asm("v_exp_f32 %0, %1" : "=v"(e) : "v"(t_));   // 2^t
                scv[st][r] = e;
                if (r==0) s0 += e; else if (r==1) s1 += e; else if (r==2) s2 += e; else s3 += e;
            }
        }
        float s_ = (s0+s1) + (s2+s3);
        s_ += __shfl_xor(s_, 16);
        s_ += __shfl_xor(s_, 32);
        if ((tid & 48) == 0) redf[w*16 + ln] = s_;
    }
    __syncthreads();                                  // bar2: redf visible
    {
        float sum = redf[ln] + redf[16+ln] + redf[32+ln] + redf[48+ln];
        inv14 = 16384.0f / sum;        // one IEEE div per thread
    }

    // ---- T14 async-stage (lean): issue phase-2 kb0-1 vd loads NOW, fenced;
    // ~200cyc L2 latency hides under the requant VALU below.
    const v4i* vb = (const v4i*)(vd + (size_t)bh*VD_BH);
    v4i gb[2][4];    // [parity][2 per kb x 2 kb]  (24 regs total with ga)
    v8s ga[2][2];
    if (PK){
        gb[0][0] = vb[(0*8 + w*2    )*64 + lane];
        gb[0][1] = vb[(0*8 + w*2 + 1)*64 + lane];
        gb[0][2] = vb[(1*8 + w*2    )*64 + lane];
        gb[0][3] = vb[(1*8 + w*2 + 1)*64 + lane];
        __builtin_amdgcn_sched_barrier(0);
    }

    // ======== group-of-8 po2 requant, in registers -> b64 rbuf stores ========
    // granule = thread's 4 s-values + partner at lane^16; gmax <= 255<<sh so no clamp.
    // XOR swizzle c' = c ^ ((ln&7)<<4) on unpadded 2048B rows (R13-validated).
    {
        const int lnr4 = (ln & 7) << 4;
        const int cbase = w*32 + qd4*4;
        unsigned short* rp = rbuf + ln*1024;
        #pragma unroll
        for (int st=0;st<16;st++){
            float v0 = rintf(scv[st][0] * inv14);
            float v1 = rintf(scv[st][1] * inv14);
            float v2 = rintf(scv[st][2] * inv14);
            float v3 = rintf(scv[st][3] * inv14);
            float g = fmaxf(fmaxf(v0,v1), fmaxf(v2,v3));
            g = fmaxf(g, __shfl_xor(g, 16));            // partner half of the granule
            int gi = max((int)g, 1);
            int x  = gi - 1;
            int e2 = 31 - __clz(x | 255);
            int sh = (e2 - 7) + ((x >> (e2 - 7)) == 255); // clip(ceil(log2(gi/255)),0,)
            float isc = __int_as_float((127 - sh) << 23); // exact 2^-sh
            float fsc = __int_as_float((127 + sh) << 23); // exact 2^sh
            unsigned b0 = __float_as_uint(rintf(v0*isc) * fsc);  // r = rq<<sh, 8 sig bits
            unsigned b1 = __float_as_uint(rintf(v1*isc) * fsc);
            unsigned b2 = __float_as_uint(rintf(v2*isc) * fsc);
            unsigned b3 = __float_as_uint(rintf(v3*isc) * fsc);
            unsigned w0 = __builtin_amdgcn_perm(b1, b0, 0x07060302u); // {bf16(v0),bf16(v1)}
            unsigned w1 = __builtin_amdgcn_perm(b3, b2, 0x07060302u);
            int c0 = (st>>1)*128 + cbase + (st&1)*16;   // col of v0 (u16 units, 4-aligned)
            *(v2u*)(rp + (c0 ^ lnr4)) = v2u{w0, w1};    // one swizzled b64 store per tile
        }
    }
    __syncthreads();                                  // bar3: rbuf ready

    // ============ phase 2: out = r @ vt^T (bf16 MFMA, lean fenced ping-pong) ==========
    // Groups of 2 kb: prefetch group g+1's 4 vd loads + 2 LDS reads while
    // computing group g's 4 MFMAs. 16 groups.
    const unsigned short* rp2 = rbuf + ln*1024;
    const int lnr4b = (ln & 7) << 4;
    v4f acc0{0,0,0,0}, acc1{0,0,0,0};
    if (PK){
        ga[0][0] = *(const v8s*)(rp2 + ((0*32 + qd4*8) ^ lnr4b));
        ga[0][1] = *(const v8s*)(rp2 + ((1*32 + qd4*8) ^ lnr4b));
        #pragma unroll
        for (int g=0; g<16; ++g){
            const int par = g & 1;
            if (g < 15){
                const int kb2 = 2*g+2, kb3 = 2*g+3;
                gb[par^1][0] = vb[(kb2*8 + w*2    )*64 + lane];
                gb[par^1][1] = vb[(kb2*8 + w*2 + 1)*64 + lane];
                gb[par^1][2] = vb[(kb3*8 + w*2    )*64 + lane];
                gb[par^1][3] = vb[(kb3*8 + w*2 + 1)*64 + lane];
                ga[par^1][0] = *(const v8s*)(rp2 + ((kb2*32 + qd4*8) ^ lnr4b));
                ga[par^1][1] = *(const v8s*)(rp2 + ((kb3*32 + qd4*8) ^ lnr4b));
            }
            __builtin_amdgcn_sched_barrier(0);        // pin loads before MFMAs
            v8s bs0, bs1, bs2, bs3;
            memcpy(&bs0, &gb[par][0], 16);
            memcpy(&bs1, &gb[par][1], 16);
            memcpy(&bs2, &gb[par][2], 16);
            memcpy(&bs3, &gb[par][3], 16);
            acc0 = __builtin_amdgcn_mfma_f32_16x16x32_bf16(ga[par][0], bs0, acc0, 0,0,0);
            acc1 = __builtin_amdgcn_mfma_f32_16x16x32_bf16(ga[par][0], bs1, acc1, 0,0,0);
            acc0 = __builtin_amdgcn_mfma_f32_16x16x32_bf16(ga[par][1], bs2, acc0, 0,0,0);
            acc1 = __builtin_amdgcn_mfma_f32_16x16x32_bf16(ga[par][1], bs3, acc1, 0,0,0);
        }
    } else {
        #pragma unroll 4
        for (int kb=0; kb<32; ++kb){
            v8s af = *(const v8s*)(rp2 + ((kb*32 + qd4*8) ^ lnr4b));
            v4i b0, b1;
            #pragma unroll
            for (int i=0;i<2;i++){
                int chan = (w*2+i)*16 + ln;
                v4i t = pack8(vt_q + (size_t)(bh*HCN + chan)*SN + kb*32 + qd4*8,
                              vt_s[(bh*HCN + chan)*128 + kb*4 + qd4]);
                if (i==0) b0 = t; else b1 = t;
            }
            v8s bs0, bs1;
            memcpy(&bs0, &b0, 16);
            memcpy(&bs1, &b1, 16);
            acc0 = __builtin_amdgcn_mfma_f32_16x16x32_bf16(af, bs0, acc0, 0,0,0);
            acc1 = __builtin_amdgcn_mfma_f32_16x16x32_bf16(af, bs1, acc1, 0,0,0);
        }
    }
    #pragma unroll
    for (int r=0;r<4;r++){
        size_t o = (size_t)(bh*TN + t0 + qd4*4 + r)*HCN + w*32 + ln;
        out[o]      = (int)rintf(acc0[r]);
        out[o + 16] = (int)rintf(acc1[r]);
    }
}

extern "C" void kernel_launch(void* const* d_in, const int* in_sizes, int n_in,
                              void* d_out, int out_size, void* d_ws, size_t ws_size,
                              hipStream_t stream) {
    const int* q_q  = (const int*)d_in[0];
    const int* q_s  = (const int*)d_in[1];
    const int* k_q  = (const int*)d_in[2];
    const int* k_s  = (const int*)d_in[3];
    const int* vt_q = (const int*)d_in[4];
    const int* vt_s = (const int*)d_in[5];
    int* out = (int*)d_out;

    unsigned char* kd = (unsigned char*)d_ws;
    unsigned char* vd = kd + (size_t)BHN*KD_BH;

    if (ws_size >= WS_NEED){
        // 16384 wave-tasks (8192 kd + 8192 vd), 4 waves/block
        digitize<<<dim3(4096), 256, 0, stream>>>(k_q,k_s,vt_q,vt_s, kd,vd);
        mha_mfma<true><<<dim3(2048), 256, 0, stream>>>(
            q_q,q_s,k_q,k_s,vt_q,vt_s, kd,vd, out);
    } else {
        mha_mfma<false><<<dim3(2048), 256, 0, stream>>>(
            q_q,q_s,k_q,k_s,vt_q,vt_s, kd,vd, out);
    }
}